// Round 18
// baseline (78.233 us; speedup 1.0000x reference)
//
#include <hip/hip_runtime.h>

// GCN 2-layer forward via two-level dst sort (fixed-cap bins -> in-place counting sort)
// + register gather. Round18: PERFECT LOAD BALANCE — 512 bins via magic-div node
// partition (bin = dst*512/N, bin size <=196), scatter = 512 equal edge slices,
// sort = 512 bins; both grids = exactly 2 blocks/CU (kills the 391-block 24% tail).
// record = (src<<8)|dstlocal. Layer-1 algebra: A_norm@(x@W1) == (A_norm@x)@W1.

#define NB    512            // number of bins == scatter blocks == sort blocks
#define SMAX  6272           // max edges per scatter slice (E/512 + align)
#define CAP   7168           // dwords per bin region; mean fill 6250, +11 sigma

__global__ void k_zero(int* __restrict__ gcursor) {
    gcursor[threadIdx.x] = 0;     // 512 threads, 1 block
}

__global__ void k_scatter(const int* __restrict__ src, const int* __restrict__ dst,
                          int* __restrict__ gcursor, int* __restrict__ records,
                          int E, int N, unsigned int M /* ceil(2^48/N) */) {
    __shared__ int cnt[NB];
    __shared__ int loff[NB];         // inclusive scan
    __shared__ int gw[NB];           // global write base - local exclusive offset
    __shared__ int stage[SMAX];      // 24.5 KB
    __shared__ unsigned short sbin[SMAX];   // 12.25 KB
    int t = threadIdx.x;             // 512 threads
    int b = blockIdx.x;              // 512 blocks
    cnt[t] = 0;
    __syncthreads();
    int e0 = (int)(((long long)E * b) >> 9) & ~3;
    int e1 = (b == NB - 1) ? E : ((int)(((long long)E * (b + 1)) >> 9) & ~3);
    int n = e1 - e0;                 // ~6250, multiple of 4
    int nv = n >> 2;
    const int4* s4p = (const int4*)(src + e0);
    const int4* d4p = (const int4*)(dst + e0);
    int4 dv0, dv1, dv2, dv3, sv0, sv1, sv2, sv3;
    int ba0,bb0,bc0,bd0, ba1,bb1,bc1,bd1, ba2,bb2,bc2,bd2, ba3,bb3,bc3,bd3;
    int ra0,rb0,rc0,rd0, ra1,rb1,rc1,rd1, ra2,rb2,rc2,rd2, ra3,rb3,rc3,rd3;
#define BIN(d) ((int)((((unsigned long long)((d) << 9)) * M) >> 48))
#define LOADIT(K) { int idx = t + (K << 9); if (idx < nv) { dv##K = d4p[idx]; sv##K = s4p[idx]; \
        ba##K = BIN(dv##K.x); ra##K = atomicAdd(&cnt[ba##K], 1); \
        bb##K = BIN(dv##K.y); rb##K = atomicAdd(&cnt[bb##K], 1); \
        bc##K = BIN(dv##K.z); rc##K = atomicAdd(&cnt[bc##K], 1); \
        bd##K = BIN(dv##K.w); rd##K = atomicAdd(&cnt[bd##K], 1); } }
    LOADIT(0) LOADIT(1) LOADIT(2) LOADIT(3)
#undef LOADIT
    __syncthreads();
    loff[t] = cnt[t];
    __syncthreads();
    for (int d = 1; d < NB; d <<= 1) {
        int a0 = (t >= d) ? loff[t - d] : 0;
        __syncthreads();
        loff[t] += a0;
        __syncthreads();
    }
    {
        int c = cnt[t];
        if (c > 0) {
            int gb = t * CAP + atomicAdd(&gcursor[t], c);
            gw[t] = gb - (loff[t] - c);
        }
    }
#define PLACE(DD, BB, SS, RK) { int st_ = (((BB) * N + 511) >> 9); \
        int slot = (loff[BB] - cnt[BB]) + (RK); \
        stage[slot] = ((SS) << 8) | ((DD) - st_); sbin[slot] = (unsigned short)(BB); }
#define STAGEIT(K) { int idx = t + (K << 9); if (idx < nv) { \
        PLACE(dv##K.x, ba##K, sv##K.x, ra##K) PLACE(dv##K.y, bb##K, sv##K.y, rb##K) \
        PLACE(dv##K.z, bc##K, sv##K.z, rc##K) PLACE(dv##K.w, bd##K, sv##K.w, rd##K) } }
    STAGEIT(0) STAGEIT(1) STAGEIT(2) STAGEIT(3)
#undef STAGEIT
#undef PLACE
#undef BIN
    __syncthreads();
#pragma unroll
    for (int it = 0; it < 13; ++it) {       // 13*512 = 6656 >= SMAX
        int i = t + (it << 9);
        if (i < n) records[gw[sbin[i]] + i] = stage[i];
    }
}

// per bin (512 thr): rank via atomic-return (phase1, int4 reads), scan -> u4/off/dend
// (x staged via LDS), re-read records (L2-hot) placing into LDS rbuf2, stream csr
// out coalesced as int4. csr aliases records. Bin b covers nodes [start(b), start(b+1)).
__global__ void k_sort(int* __restrict__ records /* = csr out */,
                       const int* __restrict__ gcursor, const float* __restrict__ x,
                       float4* __restrict__ u4, int* __restrict__ off,
                       int* __restrict__ dend, int N) {
    __shared__ int h[256];
    __shared__ int sc[256];
    __shared__ int base[256];              // local exclusive offset
    __shared__ unsigned short rrank[CAP];  // 14 KB
    __shared__ int rbuf2[CAP];             // 28 KB
    __shared__ float sx[768];              // 3 KB
    int b = blockIdx.x, t = threadIdx.x;   // 512 threads, 512 blocks
    if (t < 256) h[t] = 0;
    int node0 = (b * N + 511) >> 9;                 // start(b)
    int node1 = ((b + 1) * N + 511) >> 9;           // start(b+1)
    if (b == NB - 1) node1 = N;
    int bsz = node1 - node0;                        // <= 196
    int xn = 3 * bsz;
    for (int i = t; i < xn; i += 512) sx[i] = x[3 * node0 + i];
    __syncthreads();
    int r0 = b * CAP;
    int count = min(gcursor[b], CAP);
    int nv = count >> 2;
    const int4* rp = (const int4*)(records + r0);   // r0 16B-aligned (CAP%4==0)
    for (int v = t; v < nv; v += 512) {
        int4 r4 = rp[v];
        int ib = v << 2;
        rrank[ib]     = (unsigned short)atomicAdd(&h[r4.x & 255], 1);
        rrank[ib + 1] = (unsigned short)atomicAdd(&h[r4.y & 255], 1);
        rrank[ib + 2] = (unsigned short)atomicAdd(&h[r4.z & 255], 1);
        rrank[ib + 3] = (unsigned short)atomicAdd(&h[r4.w & 255], 1);
    }
    for (int i = (nv << 2) + t; i < count; i += 512)
        rrank[i] = (unsigned short)atomicAdd(&h[records[r0 + i] & 255], 1);
    __syncthreads();
    if (t < 256) sc[t] = h[t];
    __syncthreads();
    for (int d = 1; d < 256; d <<= 1) {
        int v = (t < 256 && t >= d) ? sc[t - d] : 0;
        __syncthreads();
        if (t < 256) sc[t] += v;
        __syncthreads();
    }
    if (t < 256) {
        int excl = sc[t] - h[t];
        base[t] = excl;
        if (t < bsz) {
            int node = node0 + t;
            off[node]  = r0 + excl;
            dend[node] = r0 + excl + h[t];
            float di = rsqrtf((float)(h[t] + 1));    // +1 self-loop
            u4[node] = make_float4(sx[3*t] * di, sx[3*t+1] * di, sx[3*t+2] * di, di);
        }
    }
    __syncthreads();
    for (int v = t; v < nv; v += 512) {
        int4 r4 = rp[v];
        int ib = v << 2;
        rbuf2[base[r4.x & 255] + rrank[ib]]     = r4.x >> 8;
        rbuf2[base[r4.y & 255] + rrank[ib + 1]] = r4.y >> 8;
        rbuf2[base[r4.z & 255] + rrank[ib + 2]] = r4.z >> 8;
        rbuf2[base[r4.w & 255] + rrank[ib + 3]] = r4.w >> 8;
    }
    for (int i = (nv << 2) + t; i < count; i += 512) {
        int r = records[r0 + i];
        rbuf2[base[r & 255] + rrank[i]] = r >> 8;
    }
    __syncthreads();
    int4* wp = (int4*)(records + r0);
    for (int v = t; v < nv; v += 512) {
        int ib = v << 2;
        wp[v] = make_int4(rbuf2[ib], rbuf2[ib + 1], rbuf2[ib + 2], rbuf2[ib + 3]);
    }
    for (int i = (nv << 2) + t; i < count; i += 512) records[r0 + i] = rbuf2[i];
}

// NOTE: csr entries are ABSOLUTE node ids (src) -> gat kernels unchanged from r17.
// 8 lanes per node, 4-deep ILP, shfl_xor octet reduce; MLP parallel across lanes.
__global__ void k_gat1(const int* __restrict__ off, const int* __restrict__ dend,
                       const int* __restrict__ csr, const float4* __restrict__ u4,
                       const float* __restrict__ W1, const float* __restrict__ b1,
                       const float* __restrict__ W2, float2* __restrict__ g2, int N) {
    __shared__ float sW1[48];
    __shared__ float sb1[16];
    __shared__ float sW2[32];
    if (threadIdx.x < 48) sW1[threadIdx.x] = W1[threadIdx.x];
    if (threadIdx.x < 16) sb1[threadIdx.x] = b1[threadIdx.x];
    if (threadIdx.x < 32) sW2[threadIdx.x] = W2[threadIdx.x];
    __syncthreads();
    int gid = blockIdx.x * blockDim.x + threadIdx.x;
    int node = gid >> 3, q = gid & 7;
    if (node >= N) return;
    int o0 = off[node], o1 = dend[node];
    float a0 = 0.f, a1 = 0.f, a2 = 0.f;
    int j = o0 + q;
    for (; j + 24 < o1; j += 32) {
        int s[4]; float4 v[4];
#pragma unroll
        for (int k = 0; k < 4; ++k) s[k] = csr[j + 8*k];
#pragma unroll
        for (int k = 0; k < 4; ++k) v[k] = u4[s[k]];
#pragma unroll
        for (int k = 0; k < 4; ++k) { a0 += v[k].x; a1 += v[k].y; a2 += v[k].z; }
    }
    for (; j < o1; j += 8) {
        float4 v = u4[csr[j]];
        a0 += v.x; a1 += v.y; a2 += v.z;
    }
    a0 += __shfl_xor(a0, 1); a0 += __shfl_xor(a0, 2); a0 += __shfl_xor(a0, 4);
    a1 += __shfl_xor(a1, 1); a1 += __shfl_xor(a1, 2); a1 += __shfl_xor(a1, 4);
    a2 += __shfl_xor(a2, 1); a2 += __shfl_xor(a2, 2); a2 += __shfl_xor(a2, 4);
    float4 self = u4[node];
    float di = self.w;
    float v0 = (a0 + self.x) * di, v1 = (a1 + self.y) * di, v2 = (a2 + self.z) * di;
    float p0 = 0.f, p1 = 0.f;
#pragma unroll
    for (int kk = 0; kk < 2; ++kk) {
        int k = q + (kk << 3);
        float tt = fmaxf(v0 * sW1[k] + v1 * sW1[16 + k] + v2 * sW1[32 + k] + sb1[k], 0.f);
        p0 += tt * sW2[2*k];
        p1 += tt * sW2[2*k + 1];
    }
    p0 += __shfl_xor(p0, 1); p0 += __shfl_xor(p0, 2); p0 += __shfl_xor(p0, 4);
    p1 += __shfl_xor(p1, 1); p1 += __shfl_xor(p1, 2); p1 += __shfl_xor(p1, 4);
    if (q == 0) g2[node] = make_float2(p0 * di, p1 * di);
}

__global__ void k_gat2(const int* __restrict__ off, const int* __restrict__ dend,
                       const int* __restrict__ csr, const float2* __restrict__ g2,
                       const float4* __restrict__ u4, const float* __restrict__ b2,
                       float2* __restrict__ out, int N) {
    int gid = blockIdx.x * blockDim.x + threadIdx.x;
    int node = gid >> 3, q = gid & 7;
    if (node >= N) return;
    int o0 = off[node], o1 = dend[node];
    float a0 = 0.f, a1 = 0.f;
    int j = o0 + q;
    for (; j + 24 < o1; j += 32) {
        int s[4]; float2 v[4];
#pragma unroll
        for (int k = 0; k < 4; ++k) s[k] = csr[j + 8*k];
#pragma unroll
        for (int k = 0; k < 4; ++k) v[k] = g2[s[k]];
#pragma unroll
        for (int k = 0; k < 4; ++k) { a0 += v[k].x; a1 += v[k].y; }
    }
    for (; j < o1; j += 8) {
        float2 v = g2[csr[j]];
        a0 += v.x; a1 += v.y;
    }
    a0 += __shfl_xor(a0, 1); a0 += __shfl_xor(a0, 2); a0 += __shfl_xor(a0, 4);
    a1 += __shfl_xor(a1, 1); a1 += __shfl_xor(a1, 2); a1 += __shfl_xor(a1, 4);
    if (q != 0) return;
    float2 self = g2[node];
    float di = u4[node].w;
    float o0f = (a0 + self.x) * di + b2[0];
    float o1f = (a1 + self.y) * di + b2[1];
    float m = fmaxf(o0f, o1f);
    float lse = m + logf(expf(o0f - m) + expf(o1f - m));
    out[node] = make_float2(o0f - lse, o1f - lse);
}

extern "C" void kernel_launch(void* const* d_in, const int* in_sizes, int n_in,
                              void* d_out, int out_size, void* d_ws, size_t ws_size,
                              hipStream_t stream) {
    const float* x  = (const float*)d_in[0];
    const int*   ei = (const int*)d_in[1];
    const float* W1 = (const float*)d_in[2];
    const float* b1 = (const float*)d_in[3];
    const float* W2 = (const float*)d_in[4];
    const float* b2 = (const float*)d_in[5];
    float* out = (float*)d_out;

    const int N = in_sizes[0] / 3;
    const int E = in_sizes[1] / 2;
    const int* src = ei;
    const int* dst = ei + E;
    // magic for bin = (dst<<9)*M >> 48 == floor(dst*512/N); exact for dst < 2^17
    const unsigned int M = (unsigned int)((281474976710656ULL + (unsigned long long)N - 1) / (unsigned long long)N);

    // ws (dwords): [gcursor 512][off N+8][dend N][records/csr NB*CAP][u4 4N][g2 2N]
    //  ~= 2KB + 0.4MB + 0.4MB + 14.7MB + 1.6MB + 0.8MB ~= 17.9 MB
    int* gcursor  = (int*)d_ws;
    int* off      = gcursor + 512;
    int* dend     = off + N + 8;
    int* records  = dend + N;                     // doubles as csr
    float4* u4    = (float4*)(records + (size_t)NB * CAP);
    float2* g2    = (float2*)(u4 + N);

    k_zero<<<1, 512, 0, stream>>>(gcursor);
    k_scatter<<<NB, 512, 0, stream>>>(src, dst, gcursor, records, E, N, M);
    k_sort<<<NB, 512, 0, stream>>>(records, gcursor, x, u4, off, dend, N);
    int nbG = ((N * 8) + 255) / 256;
    k_gat1<<<nbG, 256, 0, stream>>>(off, dend, records, u4, W1, b1, W2, g2, N);
    k_gat2<<<nbG, 256, 0, stream>>>(off, dend, records, g2, u4, b2, (float2*)out, N);
}